// Round 10
// baseline (1528.431 us; speedup 1.0000x reference)
//
#include <hip/hip_runtime.h>
#include <hip/hip_fp16.h>

#define NN 200000
#define NE 6400000
#define F_IN 20
#define F_OUT 10
#define XPH 16              // xp row stride in halves: 32B, 2 rows per cache line
#define NEG_SLOPE 0.2f
#define BN_EPS 1e-5f

#define NPB 256             // nodes per bucket = dst >> 8
#define NBUCK 782           // ceil(NN/256); 782*256 = 200192
#define CHUNK 4096          // edges per scatter block (LDS-sortable)
#define NBLK 1563           // ceil(NE/CHUNK)
#define SB 256              // scatter block size
#define NPT (CHUNK / SB)    // 16 records per thread
#define HSB 240             // stats partial blocks
#define RT 256              // creduce threads (one per node in bucket)
#define CAP 9216            // bucket region capacity: mean 8192 + 11 sigma

// ---- workspace float/int offsets ----
#define OFF_C      41
#define OFF_LOOPAE 42
#define OFF_SCALE  64
#define OFF_SHIFT  84
#define OFF_PART   128                      // HSB*40 partials
#define OFF_PEW    (OFF_PART + HSB * 40)
#define OFF_AS     (OFF_PEW + HSB)
#define OFF_AD     (OFF_AS + NN)
#define OFF_XP     (OFF_AD + NN)            // fp16 table: 8*NN floats worth, 32B-aligned
#define OFF_CNT    (OFF_XP + 8 * NN)        // NBUCK ints (zeroed per call)
#define OFF_REC    (((OFF_CNT + NBUCK) + 1) & ~1)   // NBUCK*CAP u64 records

typedef unsigned long long u64;

// ---------------- column stats of h: per-block partials ----------------
__global__ void k_hstats(const float* __restrict__ h, float* __restrict__ part) {
    float s[F_IN], q[F_IN];
#pragma unroll
    for (int f = 0; f < F_IN; ++f) { s[f] = 0.f; q[f] = 0.f; }
    for (int i = blockIdx.x * blockDim.x + threadIdx.x; i < NN;
         i += gridDim.x * blockDim.x) {
        const float4* row = (const float4*)(h + (size_t)i * F_IN);
#pragma unroll
        for (int v = 0; v < 5; ++v) {
            float4 x = row[v];
            int f = v * 4;
            s[f+0] += x.x; q[f+0] += x.x * x.x;
            s[f+1] += x.y; q[f+1] += x.y * x.y;
            s[f+2] += x.z; q[f+2] += x.z * x.z;
            s[f+3] += x.w; q[f+3] += x.w * x.w;
        }
    }
#pragma unroll
    for (int f = 0; f < F_IN; ++f)
        for (int o = 32; o > 0; o >>= 1) {
            s[f] += __shfl_down(s[f], o);
            q[f] += __shfl_down(q[f], o);
        }
    __shared__ float red[4][40];
    int t = threadIdx.x, wave = t >> 6, lane = t & 63;
    if (lane == 0) {
#pragma unroll
        for (int f = 0; f < F_IN; ++f) { red[wave][f] = s[f]; red[wave][F_IN + f] = q[f]; }
    }
    __syncthreads();
    if (t < 40) part[blockIdx.x * 40 + t] = red[0][t] + red[1][t] + red[2][t] + red[3][t];
}

// ---------------- sum of edge_weight: per-block partials ----------------
__global__ void k_ewsum(const float* __restrict__ ew, float* __restrict__ pew) {
    float s = 0.f;
    const float4* e4 = (const float4*)ew;
    const int n4 = NE / 4;
    for (int i = blockIdx.x * blockDim.x + threadIdx.x; i < n4;
         i += gridDim.x * blockDim.x) {
        float4 x = e4[i];
        s += x.x + x.y + x.z + x.w;
    }
    for (int o = 32; o > 0; o >>= 1) s += __shfl_down(s, o);
    __shared__ float red[4];
    int t = threadIdx.x;
    if ((t & 63) == 0) red[t >> 6] = s;
    __syncthreads();
    if (t == 0) pew[blockIdx.x] = red[0] + red[1] + red[2] + red[3];
}

// ---------------- finalize scalar params ----------------
__global__ void k_params(const float* __restrict__ bn_w, const float* __restrict__ bn_b,
                         const float* __restrict__ W_edge, const float* __restrict__ att_edge,
                         const float* __restrict__ part, const float* __restrict__ pew,
                         float* __restrict__ ws) {
    __shared__ float col[40];
    __shared__ float ews;
    int t = threadIdx.x;
    if (t < 40) {
        float s = 0.f;
#pragma unroll 8
        for (int b = 0; b < HSB; ++b) s += part[b * 40 + t];
        col[t] = s;
    }
    if (t == 40) {
        float s = 0.f;
#pragma unroll 8
        for (int b = 0; b < HSB; ++b) s += pew[b];
        ews = s;
    }
    __syncthreads();
    if (t < F_IN) {
        float mu  = col[t] / (float)NN;
        float var = col[F_IN + t] / (float)NN - mu * mu;
        float sc  = bn_w[t] * rsqrtf(var + BN_EPS);
        ws[OFF_SCALE + t] = sc;
        ws[OFF_SHIFT + t] = bn_b[t] - mu * sc;
    }
    if (t == 63) {
        float c = 0.f;
#pragma unroll
        for (int k = 0; k < F_OUT; ++k) c += W_edge[k] * att_edge[k];
        ws[OFF_C] = c;
        ws[OFF_LOOPAE] = c * (ews / (float)NE);
    }
}

// ---------------- per-node: BN + projection + attention; xp stored fp16 ----------------
__global__ void k_node(const float* __restrict__ h, const float* __restrict__ W,
                       const float* __restrict__ att_src, const float* __restrict__ att_dst,
                       const float* __restrict__ ws_ro, __half* __restrict__ xph,
                       float* __restrict__ a_s, float* __restrict__ a_d) {
    __shared__ float sW[F_OUT * F_IN], sAs[F_OUT], sAd[F_OUT], sSc[F_IN], sSh[F_IN];
    int t = threadIdx.x;
    if (t < F_OUT * F_IN) sW[t] = W[t];
    if (t < F_OUT) { sAs[t] = att_src[t]; sAd[t] = att_dst[t]; }
    if (t >= 224 && t < 224 + F_IN) {
        sSc[t - 224] = ws_ro[OFF_SCALE + (t - 224)];
        sSh[t - 224] = ws_ro[OFF_SHIFT + (t - 224)];
    }
    __syncthreads();
    int i = blockIdx.x * blockDim.x + t;
    if (i >= NN) return;
    float xn[F_IN];
    const float4* row = (const float4*)(h + (size_t)i * F_IN);
#pragma unroll
    for (int v = 0; v < 5; ++v) {
        float4 x = row[v];
        int f = v * 4;
        xn[f+0] = x.x * sSc[f+0] + sSh[f+0];
        xn[f+1] = x.y * sSc[f+1] + sSh[f+1];
        xn[f+2] = x.z * sSc[f+2] + sSh[f+2];
        xn[f+3] = x.w * sSc[f+3] + sSh[f+3];
    }
    float acc[F_OUT];
    float as = 0.f, ad = 0.f;
#pragma unroll
    for (int k = 0; k < F_OUT; ++k) {
        float a = 0.f;
#pragma unroll
        for (int f = 0; f < F_IN; ++f) a += sW[k * F_IN + f] * xn[f];
        acc[k] = a;
        as += a * sAs[k];
        ad += a * sAd[k];
    }
    __half2 h01 = __floats2half2_rn(acc[0], acc[1]);
    __half2 h23 = __floats2half2_rn(acc[2], acc[3]);
    __half2 h45 = __floats2half2_rn(acc[4], acc[5]);
    __half2 h67 = __floats2half2_rn(acc[6], acc[7]);
    __half2 h89 = __floats2half2_rn(acc[8], acc[9]);
    unsigned* dst = (unsigned*)(xph + (size_t)i * XPH);
    uint4 U;
    U.x = *(unsigned*)&h01; U.y = *(unsigned*)&h23;
    U.z = *(unsigned*)&h45; U.w = *(unsigned*)&h67;
    *(uint4*)dst = U;
    dst[4] = *(unsigned*)&h89;
    a_s[i] = as;
    a_d[i] = ad;
}

// ---------------- pass B: LDS counting sort per chunk + atomic reservation + run copy ----
// Stores coalesce because runs are lane-contiguous within one wave store (r9 lesson).
// Global bases come from per-bucket atomic cursors into fixed-capacity regions —
// removes bcount + 3 scan kernels entirely.
__global__ void __launch_bounds__(SB) k_scatter(
        const int* __restrict__ ei, const float* __restrict__ ew,
        const float* __restrict__ ws_ro,
        const float* __restrict__ a_s, const float* __restrict__ a_d,
        int* __restrict__ cnt, u64* __restrict__ rec) {
    __shared__ u64 sBuf[CHUNK];              // 32 KB sorted records
    __shared__ int sScan[1024];              // hist -> exclusive offsets (bins >= NBUCK are 0)
    __shared__ int sT[SB];
    __shared__ int sCur[NBUCK];
    int t = threadIdx.x, blk = blockIdx.x;
#pragma unroll
    for (int k = 0; k < 4; ++k) sScan[t + k * SB] = 0;
    __syncthreads();
    int base = blk * CHUNK;
    int lim = NE - base; if (lim > CHUNK) lim = CHUNK;
    float c = ws_ro[OFF_C];
    u64 r[NPT]; int bk[NPT];
#pragma unroll
    for (int k = 0; k < NPT; ++k) {
        int j = t + k * SB;
        bk[k] = -1;
        if (j < lim) {
            int e = base + j;
            int src = __builtin_nontemporal_load(ei + e);
            int dst = ei[NE + e];
            float w  = __builtin_nontemporal_load(ew + e);
            float logit = a_s[src] + a_d[dst] + c * w;
            logit = logit > 0.f ? logit : NEG_SLOPE * logit;
            float ex = __expf(logit);
            int b = dst >> 8;
            bk[k] = b;
            r[k] = ((u64)__float_as_uint(ex) << 32) |
                   (u64)(((unsigned)src << 8) | (unsigned)(dst & (NPB - 1)));
            atomicAdd(&sScan[b], 1);
        }
    }
    __syncthreads();
    // exclusive scan over 1024 bins: 4 serial per thread + Hillis-Steele over totals
    int b0 = 4 * t;
    int c0 = sScan[b0], c1 = sScan[b0+1], c2 = sScan[b0+2], c3 = sScan[b0+3];
    int tot = c0 + c1 + c2 + c3;
    sT[t] = tot;
    __syncthreads();
    for (int off = 1; off < SB; off <<= 1) {
        int x = (t >= off) ? sT[t - off] : 0;
        __syncthreads();
        sT[t] += x;
        __syncthreads();
    }
    int pbase = sT[t] - tot;
    sScan[b0]   = pbase;
    sScan[b0+1] = pbase + c0;
    sScan[b0+2] = pbase + c0 + c1;
    sScan[b0+3] = pbase + c0 + c1 + c2;
    __syncthreads();
    for (int i = t; i < NBUCK; i += SB) sCur[i] = sScan[i];
    __syncthreads();
    // place records into LDS in bucket-sorted order
#pragma unroll
    for (int k = 0; k < NPT; ++k) {
        if (bk[k] >= 0) {
            int p = atomicAdd(&sCur[bk[k]], 1);
            sBuf[p] = r[k];
        }
    }
    __syncthreads();
    // wave-cooperative run copy with per-bucket global reservation
    int wave = t >> 6, lane = t & 63;
    for (int b = wave; b < NBUCK; b += SB / 64) {
        int st = sScan[b];
        int len = sScan[b + 1] - st;
        if (len == 0) continue;
        int gb = 0;
        if (lane == 0) gb = atomicAdd(&cnt[b], len);
        gb = __shfl(gb, 0);
        int avail = CAP - gb; if (avail < 0) avail = 0;
        int wlen = len < avail ? len : avail;    // 11-sigma clamp
        u64* dst = rec + (size_t)b * CAP + gb;
        for (int k2 = lane; k2 < wlen; k2 += 64)
            dst[k2] = sBuf[st + k2];
    }
}

// ---------------- pass C: in-bucket counting sort + register accumulate + MLP ----------------
__device__ __forceinline__ void gath(const __half* __restrict__ xph, u64 r,
                                     float& ex, float2& f0, float2& f1,
                                     float2& f2, float2& f3, float2& f4) {
    ex = __uint_as_float((unsigned)(r >> 32));
    const unsigned* p = (const unsigned*)(xph + (size_t)((unsigned)r >> 8) * XPH);
    uint4 A = *(const uint4*)p; unsigned B = p[4];
    f0 = __half22float2(*(const __half2*)&A.x);
    f1 = __half22float2(*(const __half2*)&A.y);
    f2 = __half22float2(*(const __half2*)&A.z);
    f3 = __half22float2(*(const __half2*)&A.w);
    f4 = __half22float2(*(const __half2*)&B);
}

__global__ void __launch_bounds__(RT, 8) k_creduce(
        const float* __restrict__ ws_ro, const int* __restrict__ cnt,
        const u64* __restrict__ rec, const __half* __restrict__ xph,
        const float* __restrict__ a_s, const float* __restrict__ a_d,
        const float* __restrict__ bias,
        const float* __restrict__ fc1w, const float* __restrict__ fc1b,
        const float* __restrict__ fc2w, const float* __restrict__ fc2b,
        const float* __restrict__ fc3w, const float* __restrict__ fc3b,
        float* __restrict__ out) {
    __shared__ unsigned short sIdx[CAP];
    __shared__ int sHist[RT];                // hist -> scan (in place) -> cursor
    __shared__ float s1[100], s2[100], s3[100], sb[F_OUT], sb1[F_OUT], sb2[F_OUT], sb3[F_OUT];
    int t = threadIdx.x, b = blockIdx.x;
    sHist[t] = 0;
    if (t < 100) { s1[t] = fc1w[t]; s2[t] = fc2w[t]; s3[t] = fc3w[t]; }
    if (t >= 128 && t < 128 + F_OUT) {
        int k = t - 128;
        sb[k] = bias[k]; sb1[k] = fc1b[k]; sb2[k] = fc2b[k]; sb3[k] = fc3b[k];
    }
    __syncthreads();
    const u64* brec = rec + (size_t)b * CAP;
    int cnt_b = cnt[b];
    if (cnt_b > CAP) cnt_b = CAP;
    const unsigned* recx = (const unsigned*)brec;
    // phase 1: histogram of local node
    for (int i = t; i < cnt_b; i += RT)
        atomicAdd(&sHist[recx[2 * (size_t)i] & (NPB - 1u)], 1);
    __syncthreads();
    // phase 2: in-place Hillis-Steele exclusive scan over RT bins
    int deg = sHist[t];
    for (int off = 1; off < RT; off <<= 1) {
        int x = (t >= off) ? sHist[t - off] : 0;
        __syncthreads();
        sHist[t] += x;
        __syncthreads();
    }
    int myStart = sHist[t] - deg;
    __syncthreads();
    sHist[t] = myStart;                      // reuse as cursor
    __syncthreads();
    // phase 3: scatter record indices into node-sorted order
    for (int i = t; i < cnt_b; i += RT) {
        unsigned lo = recx[2 * (size_t)i];
        int p = atomicAdd(&sHist[lo & (NPB - 1u)], 1);
        sIdx[p] = (unsigned short)i;
    }
    __syncthreads();
    // phase 4: thread t exclusively owns node t — register accumulation, no atomics
    float den = 0.f;
    float num[F_OUT];
#pragma unroll
    for (int k = 0; k < F_OUT; ++k) num[k] = 0.f;
    int e0 = myStart + deg;
    int j = myStart;
    for (; j + 3 < e0; j += 4) {
        u64 r1 = brec[sIdx[j]];
        u64 r2 = brec[sIdx[j + 1]];
        u64 r3 = brec[sIdx[j + 2]];
        u64 r4 = brec[sIdx[j + 3]];
        float e1, e2, e3, e4;
        float2 f0, f1, f2, f3, f4, g0, g1, g2, g3, g4;
        float2 h0, h1, h2, h3, h4, k0, k1, k2, k3, k4;
        gath(xph, r1, e1, f0, f1, f2, f3, f4);
        gath(xph, r2, e2, g0, g1, g2, g3, g4);
        gath(xph, r3, e3, h0, h1, h2, h3, h4);
        gath(xph, r4, e4, k0, k1, k2, k3, k4);
        den += (e1 + e2) + (e3 + e4);
        num[0] += e1 * f0.x + e2 * g0.x + e3 * h0.x + e4 * k0.x;
        num[1] += e1 * f0.y + e2 * g0.y + e3 * h0.y + e4 * k0.y;
        num[2] += e1 * f1.x + e2 * g1.x + e3 * h1.x + e4 * k1.x;
        num[3] += e1 * f1.y + e2 * g1.y + e3 * h1.y + e4 * k1.y;
        num[4] += e1 * f2.x + e2 * g2.x + e3 * h2.x + e4 * k2.x;
        num[5] += e1 * f2.y + e2 * g2.y + e3 * h2.y + e4 * k2.y;
        num[6] += e1 * f3.x + e2 * g3.x + e3 * h3.x + e4 * k3.x;
        num[7] += e1 * f3.y + e2 * g3.y + e3 * h3.y + e4 * k3.y;
        num[8] += e1 * f4.x + e2 * g4.x + e3 * h4.x + e4 * k4.x;
        num[9] += e1 * f4.y + e2 * g4.y + e3 * h4.y + e4 * k4.y;
    }
    for (; j < e0; ++j) {
        u64 r1 = brec[sIdx[j]];
        float e1;
        float2 f0, f1, f2, f3, f4;
        gath(xph, r1, e1, f0, f1, f2, f3, f4);
        den += e1;
        num[0] += e1 * f0.x; num[1] += e1 * f0.y;
        num[2] += e1 * f1.x; num[3] += e1 * f1.y;
        num[4] += e1 * f2.x; num[5] += e1 * f2.y;
        num[6] += e1 * f3.x; num[7] += e1 * f3.y;
        num[8] += e1 * f4.x; num[9] += e1 * f4.y;
    }
    int node = b * NPB + t;
    if (node >= NN) return;                  // no barriers after this point
    float l = a_s[node] + a_d[node] + ws_ro[OFF_LOOPAE];
    l = l > 0.f ? l : NEG_SLOPE * l;
    float exs = __expf(l);
    float inv = 1.0f / (den + exs);
    const unsigned* pn = (const unsigned*)(xph + (size_t)node * XPH);
    uint4 An = *(const uint4*)pn; unsigned Bn = pn[4];
    float xn[F_OUT];
    {
        float2 f0 = __half22float2(*(const __half2*)&An.x);
        float2 f1 = __half22float2(*(const __half2*)&An.y);
        float2 f2 = __half22float2(*(const __half2*)&An.z);
        float2 f3 = __half22float2(*(const __half2*)&An.w);
        float2 f4 = __half22float2(*(const __half2*)&Bn);
        xn[0]=f0.x; xn[1]=f0.y; xn[2]=f1.x; xn[3]=f1.y; xn[4]=f2.x;
        xn[5]=f2.y; xn[6]=f3.x; xn[7]=f3.y; xn[8]=f4.x; xn[9]=f4.y;
    }
    float o[F_OUT], y1[F_OUT], y2[F_OUT];
#pragma unroll
    for (int k = 0; k < F_OUT; ++k) {
        o[k] = (num[k] + exs * xn[k]) * inv + sb[k];
        out[(size_t)node * F_OUT + k] = fmaxf(o[k], 0.f);   // embeddings
    }
#pragma unroll
    for (int k = 0; k < F_OUT; ++k) {
        float a = sb1[k];
#pragma unroll
        for (int jj = 0; jj < F_OUT; ++jj) a += s1[k * F_OUT + jj] * o[jj];
        y1[k] = fmaxf(a, 0.f);
    }
#pragma unroll
    for (int k = 0; k < F_OUT; ++k) {
        float a = sb2[k];
#pragma unroll
        for (int jj = 0; jj < F_OUT; ++jj) a += s2[k * F_OUT + jj] * y1[jj];
        y2[k] = fmaxf(a, 0.f);
    }
#pragma unroll
    for (int k = 0; k < F_OUT; ++k) {
        float a = sb3[k];
#pragma unroll
        for (int jj = 0; jj < F_OUT; ++jj) a += s3[k * F_OUT + jj] * y2[jj];
        out[(size_t)NN * F_OUT + (size_t)node * F_OUT + k] = a;   // y
    }
}

extern "C" void kernel_launch(void* const* d_in, const int* in_sizes, int n_in,
                              void* d_out, int out_size, void* d_ws, size_t ws_size,
                              hipStream_t stream) {
    const float* h        = (const float*)d_in[0];
    const int*   ei       = (const int*)  d_in[1];
    const float* ew       = (const float*)d_in[2];
    const float* bn_w     = (const float*)d_in[3];
    const float* bn_b     = (const float*)d_in[4];
    const float* W        = (const float*)d_in[5];
    const float* att_src  = (const float*)d_in[6];
    const float* att_dst  = (const float*)d_in[7];
    const float* att_edge = (const float*)d_in[8];
    const float* W_edge   = (const float*)d_in[9];
    const float* bias     = (const float*)d_in[10];
    const float* fc1w     = (const float*)d_in[11];
    const float* fc1b     = (const float*)d_in[12];
    const float* fc2w     = (const float*)d_in[13];
    const float* fc2b     = (const float*)d_in[14];
    const float* fc3w     = (const float*)d_in[15];
    const float* fc3b     = (const float*)d_in[16];
    float* ws  = (float*)d_ws;
    int*   wsi = (int*)d_ws;
    float* out = (float*)d_out;
    __half* xph = (__half*)(ws + OFF_XP);

    hipMemsetAsync(wsi + OFF_CNT, 0, NBUCK * sizeof(int), stream);
    k_hstats<<<HSB, 256, 0, stream>>>(h, ws + OFF_PART);
    k_ewsum <<<HSB, 256, 0, stream>>>(ew, ws + OFF_PEW);
    k_params<<<1, 64, 0, stream>>>(bn_w, bn_b, W_edge, att_edge,
                                   ws + OFF_PART, ws + OFF_PEW, ws);
    k_node  <<<(NN + 255) / 256, 256, 0, stream>>>(h, W, att_src, att_dst, ws,
                                                   xph, ws + OFF_AS, ws + OFF_AD);
    k_scatter<<<NBLK, SB, 0, stream>>>(ei, ew, ws, ws + OFF_AS, ws + OFF_AD,
                                       wsi + OFF_CNT, (u64*)(wsi + OFF_REC));
    k_creduce<<<NBUCK, RT, 0, stream>>>(ws, wsi + OFF_CNT, (const u64*)(wsi + OFF_REC),
                                        xph, ws + OFF_AS, ws + OFF_AD,
                                        bias, fc1w, fc1b, fc2w, fc2b, fc3w, fc3b, out);
}